// Round 1
// baseline (706.813 us; speedup 1.0000x reference)
//
#include <hip/hip_runtime.h>
#include <cstdint>
#include <cstddef>

#define E_ 8
#define D_ 1024
#define F_ 4096
#define T_ 16384
#define C_ 2048   // tokens per expert

typedef __attribute__((ext_vector_type(8))) short short8;
typedef __attribute__((ext_vector_type(4))) float f32x4;

// fp32 -> bf16 round-to-nearest-even
__device__ __forceinline__ unsigned short f2b(float f) {
  union { float f; uint32_t u; } v; v.f = f;
  uint32_t u = v.u;
  return (unsigned short)((u + 0x7FFFu + ((u >> 16) & 1u)) >> 16);
}

// tanh-approx gelu (jax.nn.gelu default approximate=True)
__device__ __forceinline__ float gelu_t(float x) {
  float u = 0.7978845608028654f * (x + 0.044715f * x * x * x);
  float e = __expf(2.0f * u);
  return 0.5f * x * (2.0f - 2.0f / (e + 1.0f));  // 0.5x(1+tanh(u))
}

__device__ __forceinline__ void gload_lds16(const void* g, void* l) {
  __builtin_amdgcn_global_load_lds(
      (__attribute__((address_space(1))) void*)g,
      (__attribute__((address_space(3))) void*)l, 16, 0, 0);
}

// ---------------- pre-pass: fp32 -> bf16 elementwise ----------------
__global__ void cvt_bf16_kernel(const float* __restrict__ in,
                                unsigned short* __restrict__ out, int n) {
  int idx = blockIdx.x * blockDim.x + threadIdx.x;
  int stride = gridDim.x * blockDim.x;
  for (int i = idx * 8; i < n; i += stride * 8) {
    float4 a = *(const float4*)(in + i);
    float4 b = *(const float4*)(in + i + 4);
    union { unsigned short s[8]; int4 v; } r;
    r.s[0] = f2b(a.x); r.s[1] = f2b(a.y); r.s[2] = f2b(a.z); r.s[3] = f2b(a.w);
    r.s[4] = f2b(b.x); r.s[5] = f2b(b.y); r.s[6] = f2b(b.z); r.s[7] = f2b(b.w);
    *(int4*)(out + i) = r.v;
  }
}

// ---------------- pre-pass: per-expert transpose + convert ----------------
// in: [E][R][Cc] fp32  ->  out: [E][Cc][R] bf16
__global__ void transpose_cvt(const float* __restrict__ in,
                              unsigned short* __restrict__ out, int R, int Cc) {
  __shared__ float tile_s[32][33];
  const int e = blockIdx.y;
  const int ctiles = Cc >> 5;
  const int rt = blockIdx.x / ctiles, ct = blockIdx.x % ctiles;
  const int r0 = rt * 32, c0 = ct * 32;
  const float* ine = in + (size_t)e * R * Cc;
  unsigned short* oute = out + (size_t)e * R * Cc;
  const int tx = threadIdx.x & 31, ty = threadIdx.x >> 5;  // ty in 0..7
#pragma unroll
  for (int q = 0; q < 4; ++q)
    tile_s[ty + q * 8][tx] = ine[(size_t)(r0 + ty + q * 8) * Cc + c0 + tx];
  __syncthreads();
#pragma unroll
  for (int q = 0; q < 4; ++q) {
    float v = tile_s[tx][ty + q * 8];
    oute[(size_t)(c0 + ty + q * 8) * R + r0 + tx] = f2b(v);
  }
}

// ---------------- batched bf16 GEMM, 128x128 tile, BK=32 ----------------
// A: [E][Mt][Kt] bf16 row-major; B: [E][Nt][Kt] bf16 (row = output column).
// EPI==1: Cout = bf16 h, apply bias+gelu. EPI==2: Cout = fp32, apply bias.
template <int Mt, int Nt, int Kt, int EPI>
__global__ __launch_bounds__(256, 2)
void gemm_bf16(const unsigned short* __restrict__ A,
               const unsigned short* __restrict__ B,
               const float* __restrict__ bias, void* __restrict__ Cout) {
  static_assert(Mt % 128 == 0 && Nt % 128 == 0 && Kt % 32 == 0, "");
  constexpr int NK = Kt / 32;
  constexpr int NBLK = Nt / 128;
  const int e = blockIdx.y;
  const int mblk = blockIdx.x / NBLK;
  const int nblk = blockIdx.x % NBLK;
  const int m0 = mblk * 128, n0 = nblk * 128;
  const unsigned short* Ae = A + (size_t)e * Mt * Kt + (size_t)m0 * Kt;
  const unsigned short* Be = B + (size_t)e * Nt * Kt + (size_t)n0 * Kt;

  // LDS: sA[2][4][128][8], sB[2][4][128][8]  (k-slot-major, 16B rows)
  __shared__ unsigned short lds[16384];  // 32 KiB

  const int tid = threadIdx.x;
  const int lane = tid & 63;
  const int wave = tid >> 6;
  const int wm = wave >> 1, wn = wave & 1;  // 2x2 wave grid, 64x64 each
  const int ls = lane >> 4, lr = lane & 15;

  f32x4 acc[4][4] = {};

  // staging: chunk c = i*256 + tid ; slot = c>>7, row = c&127
  const int cA0 = tid, cA1 = 256 + tid;
  const int ss0 = cA0 >> 7, rr0 = cA0 & 127;
  const int ss1 = cA1 >> 7, rr1 = cA1 & 127;
  const unsigned int ldsOff0 = (unsigned)(0 * 256 + wave * 64) * 8;  // ushorts
  const unsigned int ldsOff1 = (unsigned)(1 * 256 + wave * 64) * 8;

  auto stage = [&](int buf, int kt) {
    const int k0 = kt * 32;
    unsigned short* sAb = lds + buf * 4096;
    unsigned short* sBb = lds + 8192 + buf * 4096;
    gload_lds16(Ae + (size_t)rr0 * Kt + k0 + ss0 * 8, sAb + ldsOff0);
    gload_lds16(Ae + (size_t)rr1 * Kt + k0 + ss1 * 8, sAb + ldsOff1);
    gload_lds16(Be + (size_t)rr0 * Kt + k0 + ss0 * 8, sBb + ldsOff0);
    gload_lds16(Be + (size_t)rr1 * Kt + k0 + ss1 * 8, sBb + ldsOff1);
  };

  stage(0, 0);
  for (int kt = 0; kt < NK; ++kt) {
    __syncthreads();  // drains vmcnt: staged tile visible; prev reads done
    if (kt + 1 < NK) stage((kt + 1) & 1, kt + 1);
    const unsigned short* sAb = lds + (kt & 1) * 4096;
    const unsigned short* sBb = lds + 8192 + (kt & 1) * 4096;
    short8 af[4], bq[4];
#pragma unroll
    for (int m = 0; m < 4; ++m)
      af[m] = *(const short8*)(sAb + ls * 1024 + (wm * 64 + m * 16 + lr) * 8);
#pragma unroll
    for (int n = 0; n < 4; ++n)
      bq[n] = *(const short8*)(sBb + ls * 1024 + (wn * 64 + n * 16 + lr) * 8);
#pragma unroll
    for (int m = 0; m < 4; ++m)
#pragma unroll
      for (int n = 0; n < 4; ++n)
        acc[m][n] =
            __builtin_amdgcn_mfma_f32_16x16x32_bf16(af[m], bq[n], acc[m][n], 0, 0, 0);
  }

  const float* be = bias + (size_t)e * Nt + n0;
  float bv[4];
#pragma unroll
  for (int n = 0; n < 4; ++n) bv[n] = be[wn * 64 + n * 16 + lr];

  if constexpr (EPI == 1) {
    __syncthreads();  // done with staging buffers; reuse LDS as 128x128 bf16
#pragma unroll
    for (int m = 0; m < 4; ++m)
#pragma unroll
      for (int n = 0; n < 4; ++n)
#pragma unroll
        for (int i = 0; i < 4; ++i) {
          int rl = wm * 64 + m * 16 + ls * 4 + i;
          int cl = wn * 64 + n * 16 + lr;
          lds[rl * 128 + cl] = f2b(gelu_t(acc[m][n][i] + bv[n]));
        }
    __syncthreads();
    unsigned short* H = (unsigned short*)Cout;
    const int orow = tid >> 1, oseg = tid & 1;
    unsigned short* dst = H + ((size_t)e * Mt + m0 + orow) * Nt + n0 + oseg * 64;
    const unsigned short* src = lds + orow * 128 + oseg * 64;
#pragma unroll
    for (int q = 0; q < 8; ++q)
      *(int4*)(dst + q * 8) = *(const int4*)(src + q * 8);
  } else {
    float* O = (float*)Cout;
#pragma unroll
    for (int m = 0; m < 4; ++m)
#pragma unroll
      for (int n = 0; n < 4; ++n)
#pragma unroll
        for (int i = 0; i < 4; ++i) {
          int rl = wm * 64 + m * 16 + ls * 4 + i;
          int cl = wn * 64 + n * 16 + lr;
          O[((size_t)e * Mt + m0 + rl) * Nt + n0 + cl] = acc[m][n][i] + bv[n];
        }
  }
}

extern "C" void kernel_launch(void* const* d_in, const int* in_sizes, int n_in,
                              void* d_out, int out_size, void* d_ws, size_t ws_size,
                              hipStream_t stream) {
  const float* x = (const float*)d_in[0];
  const float* w1 = (const float*)d_in[1];
  const float* b1 = (const float*)d_in[2];
  const float* w2 = (const float*)d_in[3];
  const float* b2 = (const float*)d_in[4];
  float* out = (float*)d_out;

  unsigned short* ws = (unsigned short*)d_ws;
  unsigned short* xb = ws;                               // [T][D] bf16
  unsigned short* w1t = xb + (size_t)T_ * D_;            // [E][F][D] bf16
  unsigned short* w2t = w1t + (size_t)E_ * F_ * D_;      // [E][D][F] bf16
  unsigned short* h = w2t + (size_t)E_ * D_ * F_;        // [T][F] bf16

  cvt_bf16_kernel<<<2048, 256, 0, stream>>>(x, xb, T_ * D_);
  transpose_cvt<<<dim3((D_ / 32) * (F_ / 32), E_), 256, 0, stream>>>(w1, w1t, D_, F_);
  transpose_cvt<<<dim3((F_ / 32) * (D_ / 32), E_), 256, 0, stream>>>(w2, w2t, F_, D_);

  gemm_bf16<C_, F_, D_, 1>
      <<<dim3((C_ / 128) * (F_ / 128), E_), 256, 0, stream>>>(xb, w1t, b1, h);
  gemm_bf16<C_, D_, F_, 2>
      <<<dim3((C_ / 128) * (D_ / 128), E_), 256, 0, stream>>>(h, w2t, b2, out);
}

// Round 2
// 507.877 us; speedup vs baseline: 1.3917x; 1.3917x over previous
//
#include <hip/hip_runtime.h>
#include <cstdint>
#include <cstddef>

#define E_ 8
#define D_ 1024
#define F_ 4096
#define T_ 16384
#define C_ 2048   // tokens per expert

typedef __attribute__((ext_vector_type(8))) short short8;
typedef __attribute__((ext_vector_type(4))) float f32x4;

// fp32 -> bf16 round-to-nearest-even
__device__ __forceinline__ unsigned short f2b(float f) {
  union { float f; uint32_t u; } v; v.f = f;
  uint32_t u = v.u;
  return (unsigned short)((u + 0x7FFFu + ((u >> 16) & 1u)) >> 16);
}

// tanh-approx gelu (jax.nn.gelu default approximate=True)
__device__ __forceinline__ float gelu_t(float x) {
  float u = 0.7978845608028654f * (x + 0.044715f * x * x * x);
  float e = __expf(2.0f * u);
  return 0.5f * x * (2.0f - 2.0f / (e + 1.0f));  // 0.5x(1+tanh(u))
}

__device__ __forceinline__ void gload_lds16(const void* g, void* l) {
  __builtin_amdgcn_global_load_lds(
      (__attribute__((address_space(1))) void*)g,
      (__attribute__((address_space(3))) void*)l, 16, 0, 0);
}

// ---------------- pre-pass: fp32 -> bf16 elementwise ----------------
__global__ void cvt_bf16_kernel(const float* __restrict__ in,
                                unsigned short* __restrict__ out, int n) {
  int idx = blockIdx.x * blockDim.x + threadIdx.x;
  int stride = gridDim.x * blockDim.x;
  for (int i = idx * 8; i < n; i += stride * 8) {
    float4 a = *(const float4*)(in + i);
    float4 b = *(const float4*)(in + i + 4);
    union { unsigned short s[8]; int4 v; } r;
    r.s[0] = f2b(a.x); r.s[1] = f2b(a.y); r.s[2] = f2b(a.z); r.s[3] = f2b(a.w);
    r.s[4] = f2b(b.x); r.s[5] = f2b(b.y); r.s[6] = f2b(b.z); r.s[7] = f2b(b.w);
    *(int4*)(out + i) = r.v;
  }
}

// ---------------- pre-pass: per-expert transpose + convert ----------------
// in: [E][R][Cc] fp32  ->  out: [E][Cc][R] bf16
__global__ void transpose_cvt(const float* __restrict__ in,
                              unsigned short* __restrict__ out, int R, int Cc) {
  __shared__ float tile_s[32][33];
  const int e = blockIdx.y;
  const int ctiles = Cc >> 5;
  const int rt = blockIdx.x / ctiles, ct = blockIdx.x % ctiles;
  const int r0 = rt * 32, c0 = ct * 32;
  const float* ine = in + (size_t)e * R * Cc;
  unsigned short* oute = out + (size_t)e * R * Cc;
  const int tx = threadIdx.x & 31, ty = threadIdx.x >> 5;  // ty in 0..7
#pragma unroll
  for (int q = 0; q < 4; ++q)
    tile_s[ty + q * 8][tx] = ine[(size_t)(r0 + ty + q * 8) * Cc + c0 + tx];
  __syncthreads();
#pragma unroll
  for (int q = 0; q < 4; ++q) {
    float v = tile_s[tx][ty + q * 8];
    oute[(size_t)(c0 + ty + q * 8) * R + r0 + tx] = f2b(v);
  }
}

// ---------------- batched bf16 GEMM, 128x128 tile, BK=32 ----------------
// A: [E][Mt][Kt] bf16 row-major; B: [E][Nt][Kt] bf16 (row = output column).
// LDS tile: row-major [128 rows][4 chunks of 16B], XOR-swizzled:
//   LDS chunk slot s holds global k-chunk (s ^ ((row>>1)&3)).
// EPI==1: Cout = bf16 h, apply bias+gelu. EPI==2: Cout = fp32, apply bias.
template <int Mt, int Nt, int Kt, int EPI>
__global__ __launch_bounds__(256, 2)
void gemm_bf16(const unsigned short* __restrict__ A,
               const unsigned short* __restrict__ B,
               const float* __restrict__ bias, void* __restrict__ Cout) {
  static_assert(Mt % 128 == 0 && Nt % 128 == 0 && Kt % 32 == 0, "");
  constexpr int NK = Kt / 32;
  constexpr int NBLK = Nt / 128;
  const int e = blockIdx.y;
  const int mblk = blockIdx.x / NBLK;
  const int nblk = blockIdx.x % NBLK;
  const int m0 = mblk * 128, n0 = nblk * 128;
  const unsigned short* Ae = A + (size_t)e * Mt * Kt + (size_t)m0 * Kt;
  const unsigned short* Be = B + (size_t)e * Nt * Kt + (size_t)n0 * Kt;

  // LDS: sA[2][128][32], sB[2][128][32] ushorts (8KB per buffer)
  __shared__ unsigned short lds[16384];  // 32 KiB

  const int tid = threadIdx.x;
  const int lane = tid & 63;
  const int wave = tid >> 6;
  const int wm = wave >> 1, wn = wave & 1;  // 2x2 wave grid, 64x64 each
  const int ls = lane >> 4, lr = lane & 15;

  f32x4 acc[4][4] = {};

  // staging: linear LDS chunk c = i*256 + tid maps to (row = c>>2, slot = c&3);
  // that slot holds global k-chunk (slot ^ ((row>>1)&3)).  4 lanes cover one
  // row's contiguous 64B (permuted within) -> coalesced 64B segments.
  const int cA0 = tid, cA1 = 256 + tid;
  const int r0_ = cA0 >> 2, g0_ = (cA0 & 3) ^ ((r0_ >> 1) & 3);
  const int r1_ = cA1 >> 2, g1_ = (cA1 & 3) ^ ((r1_ >> 1) & 3);
  const unsigned int ldsOff0 = (unsigned)(0 * 256 + wave * 64) * 8;  // ushorts
  const unsigned int ldsOff1 = (unsigned)(1 * 256 + wave * 64) * 8;

  auto stage = [&](int buf, int kt) {
    const int k0 = kt * 32;
    unsigned short* sAb = lds + buf * 4096;
    unsigned short* sBb = lds + 8192 + buf * 4096;
    gload_lds16(Ae + (size_t)r0_ * Kt + k0 + g0_ * 8, sAb + ldsOff0);
    gload_lds16(Ae + (size_t)r1_ * Kt + k0 + g1_ * 8, sAb + ldsOff1);
    gload_lds16(Be + (size_t)r0_ * Kt + k0 + g0_ * 8, sBb + ldsOff0);
    gload_lds16(Be + (size_t)r1_ * Kt + k0 + g1_ * 8, sBb + ldsOff1);
  };

  // fragment read swizzle: want k-chunk ls of row; it lives at slot ls ^ ((row>>1)&3).
  // row = (wm|wn)*64 + m*16 + lr -> (row>>1)&3 == (lr>>1)&3  (m*16, w*64 are mult of 8)
  const int swz = ls ^ ((lr >> 1) & 3);

  stage(0, 0);
  for (int kt = 0; kt < NK; ++kt) {
    __syncthreads();  // drains vmcnt: staged tile visible; prev reads done
    if (kt + 1 < NK) stage((kt + 1) & 1, kt + 1);
    const unsigned short* sAb = lds + (kt & 1) * 4096;
    const unsigned short* sBb = lds + 8192 + (kt & 1) * 4096;
    short8 af[4], bq[4];
#pragma unroll
    for (int m = 0; m < 4; ++m)
      af[m] = *(const short8*)(sAb + (wm * 64 + m * 16 + lr) * 32 + swz * 8);
#pragma unroll
    for (int n = 0; n < 4; ++n)
      bq[n] = *(const short8*)(sBb + (wn * 64 + n * 16 + lr) * 32 + swz * 8);
#pragma unroll
    for (int m = 0; m < 4; ++m)
#pragma unroll
      for (int n = 0; n < 4; ++n)
        acc[m][n] =
            __builtin_amdgcn_mfma_f32_16x16x32_bf16(af[m], bq[n], acc[m][n], 0, 0, 0);
  }

  const float* be = bias + (size_t)e * Nt + n0;
  float bv[4];
#pragma unroll
  for (int n = 0; n < 4; ++n) bv[n] = be[wn * 64 + n * 16 + lr];

  if constexpr (EPI == 1) {
    __syncthreads();  // done with staging buffers; reuse LDS as 128x128 bf16
#pragma unroll
    for (int m = 0; m < 4; ++m)
#pragma unroll
      for (int n = 0; n < 4; ++n)
#pragma unroll
        for (int i = 0; i < 4; ++i) {
          int rl = wm * 64 + m * 16 + ls * 4 + i;
          int cl = wn * 64 + n * 16 + lr;
          lds[rl * 128 + cl] = f2b(gelu_t(acc[m][n][i] + bv[n]));
        }
    __syncthreads();
    unsigned short* H = (unsigned short*)Cout;
    const int orow = tid >> 1, oseg = tid & 1;
    unsigned short* dst = H + ((size_t)e * Mt + m0 + orow) * Nt + n0 + oseg * 64;
    const unsigned short* src = lds + orow * 128 + oseg * 64;
#pragma unroll
    for (int q = 0; q < 8; ++q)
      *(int4*)(dst + q * 8) = *(const int4*)(src + q * 8);
  } else {
    float* O = (float*)Cout;
#pragma unroll
    for (int m = 0; m < 4; ++m)
#pragma unroll
      for (int n = 0; n < 4; ++n)
#pragma unroll
        for (int i = 0; i < 4; ++i) {
          int rl = wm * 64 + m * 16 + ls * 4 + i;
          int cl = wn * 64 + n * 16 + lr;
          O[((size_t)e * Mt + m0 + rl) * Nt + n0 + cl] = acc[m][n][i] + bv[n];
        }
  }
}

extern "C" void kernel_launch(void* const* d_in, const int* in_sizes, int n_in,
                              void* d_out, int out_size, void* d_ws, size_t ws_size,
                              hipStream_t stream) {
  const float* x = (const float*)d_in[0];
  const float* w1 = (const float*)d_in[1];
  const float* b1 = (const float*)d_in[2];
  const float* w2 = (const float*)d_in[3];
  const float* b2 = (const float*)d_in[4];
  float* out = (float*)d_out;

  unsigned short* ws = (unsigned short*)d_ws;
  unsigned short* xb = ws;                               // [T][D] bf16
  unsigned short* w1t = xb + (size_t)T_ * D_;            // [E][F][D] bf16
  unsigned short* w2t = w1t + (size_t)E_ * F_ * D_;      // [E][D][F] bf16
  unsigned short* h = w2t + (size_t)E_ * D_ * F_;        // [T][F] bf16

  cvt_bf16_kernel<<<2048, 256, 0, stream>>>(x, xb, T_ * D_);
  transpose_cvt<<<dim3((D_ / 32) * (F_ / 32), E_), 256, 0, stream>>>(w1, w1t, D_, F_);
  transpose_cvt<<<dim3((F_ / 32) * (D_ / 32), E_), 256, 0, stream>>>(w2, w2t, F_, D_);

  gemm_bf16<C_, F_, D_, 1>
      <<<dim3((C_ / 128) * (F_ / 128), E_), 256, 0, stream>>>(xb, w1t, b1, h);
  gemm_bf16<C_, D_, F_, 2>
      <<<dim3((C_ / 128) * (D_ / 128), E_), 256, 0, stream>>>(h, w2t, b2, out);
}

// Round 3
// 434.963 us; speedup vs baseline: 1.6250x; 1.1676x over previous
//
#include <hip/hip_runtime.h>
#include <cstdint>
#include <cstddef>

#define E_ 8
#define D_ 1024
#define F_ 4096
#define T_ 16384
#define C_ 2048   // tokens per expert

typedef __attribute__((ext_vector_type(8))) short short8;
typedef __attribute__((ext_vector_type(4))) float f32x4;

// fp32 -> bf16 round-to-nearest-even
__device__ __forceinline__ unsigned short f2b(float f) {
  union { float f; uint32_t u; } v; v.f = f;
  uint32_t u = v.u;
  return (unsigned short)((u + 0x7FFFu + ((u >> 16) & 1u)) >> 16);
}

// tanh-approx gelu (jax.nn.gelu default approximate=True)
__device__ __forceinline__ float gelu_t(float x) {
  float u = 0.7978845608028654f * (x + 0.044715f * x * x * x);
  float e = __expf(2.0f * u);
  return 0.5f * x * (2.0f - 2.0f / (e + 1.0f));  // 0.5x(1+tanh(u))
}

__device__ __forceinline__ void gload_lds16(const void* g, void* l) {
  __builtin_amdgcn_global_load_lds(
      (__attribute__((address_space(1))) void*)g,
      (__attribute__((address_space(3))) void*)l, 16, 0, 0);
}

#define MEMFENCE() asm volatile("" ::: "memory")
#define BAR() do { MEMFENCE(); __builtin_amdgcn_s_barrier(); MEMFENCE(); } while (0)

// ---------------- pre-pass: fp32 -> bf16 elementwise ----------------
__global__ void cvt_bf16_kernel(const float* __restrict__ in,
                                unsigned short* __restrict__ out, int n) {
  int idx = blockIdx.x * blockDim.x + threadIdx.x;
  int stride = gridDim.x * blockDim.x;
  for (int i = idx * 8; i < n; i += stride * 8) {
    float4 a = *(const float4*)(in + i);
    float4 b = *(const float4*)(in + i + 4);
    union { unsigned short s[8]; int4 v; } r;
    r.s[0] = f2b(a.x); r.s[1] = f2b(a.y); r.s[2] = f2b(a.z); r.s[3] = f2b(a.w);
    r.s[4] = f2b(b.x); r.s[5] = f2b(b.y); r.s[6] = f2b(b.z); r.s[7] = f2b(b.w);
    *(int4*)(out + i) = r.v;
  }
}

// ---------------- pre-pass: per-expert transpose + convert ----------------
// in: [E][R][Cc] fp32  ->  out: [E][Cc][R] bf16
__global__ void transpose_cvt(const float* __restrict__ in,
                              unsigned short* __restrict__ out, int R, int Cc) {
  __shared__ float tile_s[32][33];
  const int e = blockIdx.y;
  const int ctiles = Cc >> 5;
  const int rt = blockIdx.x / ctiles, ct = blockIdx.x % ctiles;
  const int r0 = rt * 32, c0 = ct * 32;
  const float* ine = in + (size_t)e * R * Cc;
  unsigned short* oute = out + (size_t)e * R * Cc;
  const int tx = threadIdx.x & 31, ty = threadIdx.x >> 5;  // ty in 0..7
#pragma unroll
  for (int q = 0; q < 4; ++q)
    tile_s[ty + q * 8][tx] = ine[(size_t)(r0 + ty + q * 8) * Cc + c0 + tx];
  __syncthreads();
#pragma unroll
  for (int q = 0; q < 4; ++q) {
    float v = tile_s[tx][ty + q * 8];
    oute[(size_t)(c0 + ty + q * 8) * R + r0 + tx] = f2b(v);
  }
}

// ---------------- 256x256 batched bf16 GEMM, BK=32, ring-4 pipeline ------
// A: [E][Mt][Kt] bf16 row-major; B: [E][Nt][Kt] bf16 (row = output column).
// 512 threads = 8 waves (2M x 4N), per-wave 128x64 output, acc[8][4].
// LDS: 4 ring buffers x (A 256x32 + B 256x32) bf16 = 128 KiB.
// Chunk swizzle: LDS[row][slot] holds global k-chunk (slot ^ (row&3)).
// EPI==1: Cout = bf16 h, bias+gelu, LDS-bounce store. EPI==2: fp32, bias.
template <int Mt, int Nt, int Kt, int EPI>
__global__ __launch_bounds__(512, 2)
void gemm256(const unsigned short* __restrict__ A,
             const unsigned short* __restrict__ B,
             const float* __restrict__ bias, void* __restrict__ Cout) {
  constexpr int NT = Kt / 32;
  constexpr int MB = Mt / 256, NB = Nt / 256;
  static_assert(NT >= 3 && Mt % 256 == 0 && Nt % 256 == 0, "");

  // bijective XCD swizzle (nwg % 8 == 0 for all our grids)
  const int nwg = E_ * MB * NB;
  const int bid = blockIdx.x;
  const int swz = (bid & 7) * (nwg >> 3) + (bid >> 3);
  const int e = swz / (MB * NB);
  const int rem = swz % (MB * NB);
  const int mblk = rem / NB, nblk = rem % NB;

  const unsigned short* Ae = A + ((size_t)e * Mt + mblk * 256) * Kt;
  const unsigned short* Be = B + ((size_t)e * Nt + nblk * 256) * Kt;

  __shared__ unsigned short lds[65536];  // 128 KiB

  const int tid = threadIdx.x;
  const int lane = tid & 63, wave = tid >> 6;
  const int wm = wave >> 2, wn = wave & 3;  // 2 x 4 wave grid
  const int ls = lane >> 4, lr = lane & 15;

  // staging geometry: chunk c in [0,1024): row = c>>2, slot = c&3,
  // global k-chunk g = slot ^ (row&3); LDS linear dest = c*16B.
  const int c0 = tid, c1 = 512 + tid;
  const int r0 = c0 >> 2, g0 = (c0 & 3) ^ (r0 & 3);
  const int r1 = c1 >> 2, g1 = (c1 & 3) ^ (r1 & 3);

  auto stage = [&](int t) {
    unsigned short* sA = lds + (t & 3) * 16384;
    unsigned short* sB = sA + 8192;
    const int k0 = t * 32;
    gload_lds16(Ae + (size_t)r0 * Kt + k0 + g0 * 8, sA + c0 * 8);
    gload_lds16(Ae + (size_t)r1 * Kt + k0 + g1 * 8, sA + c1 * 8);
    gload_lds16(Be + (size_t)r0 * Kt + k0 + g0 * 8, sB + c0 * 8);
    gload_lds16(Be + (size_t)r1 * Kt + k0 + g1 * 8, sB + c1 * 8);
  };

  f32x4 acc[8][4] = {};
  const int sw = ls ^ (lr & 3);  // fragment read slot (row&3 == lr&3)

  stage(0); stage(1); stage(2);

  for (int t = 0; t < NT; ++t) {
    // own stagings for tile t landed; allow newer tiles in flight (T4)
    if (t + 2 < NT)      asm volatile("s_waitcnt vmcnt(8)" ::: "memory");
    else if (t + 1 < NT) asm volatile("s_waitcnt vmcnt(4)" ::: "memory");
    else                 asm volatile("s_waitcnt vmcnt(0)" ::: "memory");
    __builtin_amdgcn_s_barrier();  // all waves: tile t visible; buf (t+3)&3 free
    MEMFENCE();
    if (t + 3 < NT) stage(t + 3);

    const unsigned short* sA = lds + (t & 3) * 16384;
    const unsigned short* sB = sA + 8192;
    short8 af[8], bf[4];
#pragma unroll
    for (int m = 0; m < 8; ++m)
      af[m] = *(const short8*)(sA + (wm * 128 + m * 16 + lr) * 32 + sw * 8);
#pragma unroll
    for (int n = 0; n < 4; ++n)
      bf[n] = *(const short8*)(sB + (wn * 64 + n * 16 + lr) * 32 + sw * 8);

    __builtin_amdgcn_s_setprio(1);
#pragma unroll
    for (int m = 0; m < 8; ++m)
#pragma unroll
      for (int n = 0; n < 4; ++n)
        acc[m][n] =
            __builtin_amdgcn_mfma_f32_16x16x32_bf16(af[m], bf[n], acc[m][n], 0, 0, 0);
    __builtin_amdgcn_s_setprio(0);
  }
  BAR();  // all reads of LDS done before epilogue reuse

  const float* be = bias + (size_t)e * Nt + nblk * 256;
  float bv[4];
#pragma unroll
  for (int n = 0; n < 4; ++n) bv[n] = be[wn * 64 + n * 16 + lr];

  if constexpr (EPI == 1) {
    // bounce: lds as [256][256] ushort, 16B-chunk XOR swizzle (ch ^= row&7)
#pragma unroll
    for (int m = 0; m < 8; ++m)
#pragma unroll
      for (int n = 0; n < 4; ++n)
#pragma unroll
        for (int i = 0; i < 4; ++i) {
          int row = wm * 128 + m * 16 + ls * 4 + i;
          int col = wn * 64 + n * 16 + lr;
          lds[row * 256 + (((col >> 3) ^ (row & 7)) << 3) + (col & 7)] =
              f2b(gelu_t(acc[m][n][i] + bv[n]));
        }
    BAR();
    unsigned short* H = (unsigned short*)Cout;
#pragma unroll
    for (int j = 0; j < 16; ++j) {
      int row = j * 16 + wave * 2 + (lane >> 5);
      int ch = lane & 31;
      int sc = ch ^ (row & 7);
      unsigned short* dst =
          H + ((size_t)e * Mt + mblk * 256 + row) * Nt + nblk * 256 + ch * 8;
      *(int4*)dst = *(const int4*)(lds + row * 256 + sc * 8);
    }
  } else {
    float* O = (float*)Cout;
#pragma unroll
    for (int m = 0; m < 8; ++m)
#pragma unroll
      for (int n = 0; n < 4; ++n)
#pragma unroll
        for (int i = 0; i < 4; ++i) {
          int row = wm * 128 + m * 16 + ls * 4 + i;
          int col = wn * 64 + n * 16 + lr;
          O[((size_t)e * Mt + mblk * 256 + row) * Nt + nblk * 256 + col] =
              acc[m][n][i] + bv[n];
        }
  }
}

extern "C" void kernel_launch(void* const* d_in, const int* in_sizes, int n_in,
                              void* d_out, int out_size, void* d_ws, size_t ws_size,
                              hipStream_t stream) {
  const float* x = (const float*)d_in[0];
  const float* w1 = (const float*)d_in[1];
  const float* b1 = (const float*)d_in[2];
  const float* w2 = (const float*)d_in[3];
  const float* b2 = (const float*)d_in[4];
  float* out = (float*)d_out;

  unsigned short* ws = (unsigned short*)d_ws;
  unsigned short* xb = ws;                               // [T][D] bf16
  unsigned short* w1t = xb + (size_t)T_ * D_;            // [E][F][D] bf16
  unsigned short* w2t = w1t + (size_t)E_ * F_ * D_;      // [E][D][F] bf16
  unsigned short* h = w2t + (size_t)E_ * D_ * F_;        // [T][F] bf16

  cvt_bf16_kernel<<<2048, 256, 0, stream>>>(x, xb, T_ * D_);
  transpose_cvt<<<dim3((D_ / 32) * (F_ / 32), E_), 256, 0, stream>>>(w1, w1t, D_, F_);
  transpose_cvt<<<dim3((F_ / 32) * (D_ / 32), E_), 256, 0, stream>>>(w2, w2t, F_, D_);

  gemm256<C_, F_, D_, 1>
      <<<E_ * (C_ / 256) * (F_ / 256), 512, 0, stream>>>(xb, w1t, b1, h);
  gemm256<C_, D_, F_, 2>
      <<<E_ * (C_ / 256) * (D_ / 256), 512, 0, stream>>>(h, w2t, b2, out);
}